// Round 2
// 921.761 us; speedup vs baseline: 1.0924x; 1.0924x over previous
//
#include <hip/hip_runtime.h>

// Problem constants
#define DD   768          // feature dim
#define BB   256          // batch
#define NN   196          // tokens per modality
#define KK1  112          // intra top-k
#define KK2  224          // inter top-k
#define RTOT (BB*3)       // 768 rows (b,modality/query)
#define CAND (2*NN)       // 392 inter candidates per query

// native clang vector for nontemporal builtins (HIP float4 is rejected)
typedef float vfloat4 __attribute__((ext_vector_type(4)));

// -------- workspace layout (bytes) --------
// Qh double[768*768] @ 0        (4,718,592)
// Td double[768*768] @ 4718592  (4,718,592)
// total ~9.4 MB (scores/mask now live in LDS of the fused kernel)

// ---------------------------------------------------------------------------
// GEMM1: Qh[r,e] = sum_d G[r,d]*Wq[e,d] + bq[e]   (r = b*3+q, G gathered)
// ---------------------------------------------------------------------------
__global__ __launch_bounds__(256) void gemm_q(
    const float* __restrict__ g0, const float* __restrict__ g1,
    const float* __restrict__ g2, const float* __restrict__ Wq,
    const float* __restrict__ bq, double* __restrict__ Qh)
{
    __shared__ float As[32][33];
    __shared__ float Ws[32][33];
    const int t  = threadIdx.x;
    const int tx = t & 15, ty = t >> 4;
    const int i0 = blockIdx.y * 32, j0 = blockIdx.x * 32;
    double a00 = 0, a01 = 0, a10 = 0, a11 = 0;
    for (int kk = 0; kk < DD; kk += 32) {
        for (int s = 0; s < 4; ++s) {
            int idx = t + s * 256;
            int r = idx >> 5, c = idx & 31;
            int row = i0 + r;
            int b = row / 3, q = row - b * 3;
            const float* gp = (q == 0) ? g0 : (q == 1) ? g1 : g2;
            As[r][c] = gp[b * DD + kk + c];
            Ws[r][c] = Wq[(j0 + r) * DD + kk + c];
        }
        __syncthreads();
        for (int k = 0; k < 32; ++k) {
            double x0 = (double)As[ty][k],      x1 = (double)As[ty + 16][k];
            double y0 = (double)Ws[tx][k],      y1 = (double)Ws[tx + 16][k];
            a00 += x0 * y0; a01 += x0 * y1; a10 += x1 * y0; a11 += x1 * y1;
        }
        __syncthreads();
    }
    Qh[(i0 + ty) * DD + j0 + tx]           = a00 + (double)bq[j0 + tx];
    Qh[(i0 + ty) * DD + j0 + tx + 16]      = a01 + (double)bq[j0 + tx + 16];
    Qh[(i0 + ty + 16) * DD + j0 + tx]      = a10 + (double)bq[j0 + tx];
    Qh[(i0 + ty + 16) * DD + j0 + tx + 16] = a11 + (double)bq[j0 + tx + 16];
}

// ---------------------------------------------------------------------------
// GEMM2: Td[r,d] = sum_e Qh[r,e]*Wk[e,d]
// ---------------------------------------------------------------------------
__global__ __launch_bounds__(256) void gemm_t(
    const double* __restrict__ Qh, const float* __restrict__ Wk,
    double* __restrict__ Td)
{
    __shared__ double As[32][33];
    __shared__ float  Ws[32][33];
    const int t  = threadIdx.x;
    const int tx = t & 15, ty = t >> 4;
    const int i0 = blockIdx.y * 32, j0 = blockIdx.x * 32;
    double a00 = 0, a01 = 0, a10 = 0, a11 = 0;
    for (int kk = 0; kk < DD; kk += 32) {
        for (int s = 0; s < 4; ++s) {
            int idx = t + s * 256;
            int r = idx >> 5, c = idx & 31;
            As[r][c] = Qh[(i0 + r) * DD + kk + c];
            Ws[r][c] = Wk[(kk + r) * DD + j0 + c];
        }
        __syncthreads();
        for (int k = 0; k < 32; ++k) {
            double x0 = As[ty][k],            x1 = As[ty + 16][k];
            double y0 = (double)Ws[k][tx],    y1 = (double)Ws[k][tx + 16];
            a00 += x0 * y0; a01 += x0 * y1; a10 += x1 * y0; a11 += x1 * y1;
        }
        __syncthreads();
    }
    Td[(i0 + ty) * DD + j0 + tx]           = a00;
    Td[(i0 + ty) * DD + j0 + tx + 16]      = a01;
    Td[(i0 + ty + 16) * DD + j0 + tx]      = a10;
    Td[(i0 + ty + 16) * DD + j0 + tx + 16] = a11;
}

// ---------------------------------------------------------------------------
// Fused score + rank + apply: one block per batch b (256 blocks x 1024 thr).
// Phase 2 reads each patch row ONCE, copies it to out (NT store) while
// accumulating the 3 fp64 dots (identical lane schedule / expression shape /
// shfl tree as the verified score_kernel -> bit-identical scores).
// Phase 3 ranks entirely in LDS (identical comparisons to rank_intra/inter).
// Phase 4 overwrites only the ~8% unselected rows with zeros (same
// thread writes the same addresses as phase 2 -> program-order safe).
// ---------------------------------------------------------------------------
__global__ __launch_bounds__(1024) void fused_score_rank_apply(
    const float* __restrict__ p0, const float* __restrict__ p1,
    const float* __restrict__ p2, const float* __restrict__ g0,
    const float* __restrict__ g1, const float* __restrict__ g2,
    const double* __restrict__ Td, float* __restrict__ out)
{
    const int b = blockIdx.x;
    __shared__ float  Gf[3][DD];        //  9.2 KB (f32 exact; cast on use)
    __shared__ double Tq[3][DD];        // 18.4 KB
    __shared__ double Li[3][NN];        //  4.7 KB intra logits
    __shared__ double Le[3][CAND];      //  9.4 KB inter logits
    __shared__ unsigned char msk[3][NN];

    // ---- phase 1: stage globals and Td rows ----
    for (int d = threadIdx.x; d < DD; d += 1024) {
        Gf[0][d] = g0[b * DD + d];
        Gf[1][d] = g1[b * DD + d];
        Gf[2][d] = g2[b * DD + d];
        Tq[0][d] = Td[(b * 3 + 0) * DD + d];
        Tq[1][d] = Td[(b * 3 + 1) * DD + d];
        Tq[2][d] = Td[(b * 3 + 2) * DD + d];
    }
    if (threadIdx.x < 3 * NN) (&msk[0][0])[threadIdx.x] = 0;
    __syncthreads();

    const int wave = threadIdx.x >> 6, lane = threadIdx.x & 63;

    // ---- phase 2: score all 588 rows, copy patch -> out on the fly ----
    for (int r = wave; r < 3 * NN; r += 16) {
        const int m = r / NN, n = r - m * NN;
        const float* pp = (m == 0) ? p0 : (m == 1) ? p1 : p2;
        const vfloat4* row = (const vfloat4*)(pp + (size_t)(b * NN + n) * DD);
        vfloat4* orow = (vfloat4*)(out + ((size_t)m * (BB * NN) + b * NN + n) * (size_t)DD);
        const int qa = (m == 0) ? 1 : 0;
        const int qb = (m == 2) ? 1 : 2;
        const int slota = m - (m > qa ? 1 : 0);
        const int slotb = m - (m > qb ? 1 : 0);
        double s0 = 0, s1 = 0, s2 = 0;
        for (int c = lane; c < DD / 4; c += 64) {
            vfloat4 v = row[c];
            __builtin_nontemporal_store(v, &orow[c]);
            const int d = c * 4;
            s0 += (double)Gf[m][d]     * (double)v[0] + (double)Gf[m][d + 1] * (double)v[1]
                + (double)Gf[m][d + 2] * (double)v[2] + (double)Gf[m][d + 3] * (double)v[3];
            s1 += Tq[qa][d]     * (double)v[0] + Tq[qa][d + 1] * (double)v[1]
                + Tq[qa][d + 2] * (double)v[2] + Tq[qa][d + 3] * (double)v[3];
            s2 += Tq[qb][d]     * (double)v[0] + Tq[qb][d + 1] * (double)v[1]
                + Tq[qb][d + 2] * (double)v[2] + Tq[qb][d + 3] * (double)v[3];
        }
        for (int off = 32; off > 0; off >>= 1) {
            s0 += __shfl_down(s0, off);
            s1 += __shfl_down(s1, off);
            s2 += __shfl_down(s2, off);
        }
        if (lane == 0) {
            Li[m][n] = s0;
            Le[qa][slota * NN + n] = s1;
            Le[qb][slotb * NN + n] = s2;
        }
    }
    __syncthreads();

    // ---- phase 3a: intra ranks (588 threads, 196-way scan, broadcast reads)
    if (threadIdx.x < 3 * NN) {
        const int m = threadIdx.x / NN, n = threadIdx.x - m * NN;
        const double v = Li[m][n];
        int rank = 0;
        for (int j = 0; j < NN; ++j) {
            double u = Li[m][j];
            rank += (u > v) || (u == v && j < n);
        }
        if (rank < KK1) msk[m][n] = 1;
    }
    // ---- phase 3b: inter ranks (1176 entries, 392-way scan) ----
    for (int t = threadIdx.x; t < 3 * CAND; t += 1024) {
        const int q = t / CAND, c = t - q * CAND;
        const double v = Le[q][c];
        int rank = 0;
        for (int j = 0; j < CAND; ++j) {
            double u = Le[q][j];
            rank += (u > v) || (u == v && j < c);
        }
        if (rank < KK2) {
            const int ma = (q == 0) ? 1 : 0;
            const int mb = (q == 2) ? 1 : 2;
            const int mm  = (c < NN) ? ma : mb;
            const int tok = (c < NN) ? c : c - NN;
            msk[mm][tok] = 1;   // only ever writes 1; benign races
        }
    }
    __syncthreads();

    // ---- phase 4: zero the unselected rows (same thread->address map as
    //      phase 2's copy, so the overwrite is program-ordered) ----
    for (int r = wave; r < 3 * NN; r += 16) {
        const int m = r / NN, n = r - m * NN;
        if (!msk[m][n]) {
            vfloat4* orow = (vfloat4*)(out + ((size_t)m * (BB * NN) + b * NN + n) * (size_t)DD);
            const vfloat4 z = {0.f, 0.f, 0.f, 0.f};
            for (int c = lane; c < DD / 4; c += 64)
                __builtin_nontemporal_store(z, &orow[c]);
        }
    }
}

extern "C" void kernel_launch(void* const* d_in, const int* in_sizes, int n_in,
                              void* d_out, int out_size, void* d_ws, size_t ws_size,
                              hipStream_t stream) {
    const float* p0 = (const float*)d_in[0];   // rgb_patches
    const float* p1 = (const float*)d_in[1];   // nir_patches
    const float* p2 = (const float*)d_in[2];   // tir_patches
    const float* g0 = (const float*)d_in[3];   // rgb_global
    const float* g1 = (const float*)d_in[4];   // nir_global
    const float* g2 = (const float*)d_in[5];   // tir_global
    const float* Wq = (const float*)d_in[6];
    const float* bq = (const float*)d_in[7];
    const float* Wk = (const float*)d_in[8];
    // d_in[9] = bk: per-(b,q)-row constant across all candidates -> cannot
    // affect top-k ordering; intentionally unused.

    char* ws = (char*)d_ws;
    double* Qh = (double*)(ws);
    double* Td = (double*)(ws + 4718592);

    dim3 ggrid(DD / 32, RTOT / 32);   // (24, 24)
    gemm_q<<<ggrid, 256, 0, stream>>>(g0, g1, g2, Wq, bq, Qh);
    gemm_t<<<ggrid, 256, 0, stream>>>(Qh, Wk, Td);
    fused_score_rank_apply<<<BB, 1024, 0, stream>>>(p0, p1, p2, g0, g1, g2, Td, (float*)d_out);
}